// Round 4
// baseline (178.080 us; speedup 1.0000x reference)
//
#include <hip/hip_runtime.h>

// Embedding-bag: out[b,:] = bias + sum_k vals[b,k] * weight[ics[b,k],:]
// B=16384, K=32, N_OUT=256.
//
// - 8 column-slices of 32 cols; slice = blockIdx % 8 -> XCD round-robin;
//   per-XCD gather slab = 41024*32*4B = 5.25 MiB (~81% L2 hit, measured R2).
// - Wave = 8 rows x 8 lanes (float4 each). Indices/values loaded directly
//   per lane (8 lanes of a row-group hit the same address -> L1 broadcast);
//   no DS-pipe shuffles in the gather dependency chain.
// - K split into 4 batches of 8 gathers, double-buffered in registers, with
//   __builtin_amdgcn_sched_barrier(0) fences so the scheduler CANNOT sink
//   the loads into the FMA region (R2/R3: VGPR=36 proved it did exactly
//   that, leaving ~3 loads in flight -> latency-bound at 60 cyc/gather).

constexpr int K = 32;

__global__ __launch_bounds__(256, 4) void FeatureTransformer_45896020525219_kernel(
    const int* __restrict__ ics,
    const float* __restrict__ vals,
    const float4* __restrict__ w4,     // [N_IN * 64]
    const float4* __restrict__ bias4,  // [64]
    float4* __restrict__ out4,         // [B * 64]
    int B)
{
    const int lane   = threadIdx.x & 63;
    const int wave   = threadIdx.x >> 6;
    const int slice  = blockIdx.x & 7;   // -> XCD (locality heuristic)
    const int rowblk = blockIdx.x >> 3;

    const int r  = lane >> 3;            // local row 0..7
    const int c4 = lane & 7;             // float4-column within the 32-col slice
    const int b  = rowblk * 32 + wave * 8 + r;
    if (b >= B) return;

    const int colbase = slice * 8 + c4;  // float4 index within the 64 per row

    const int4*   icsr = (const int4*)  (ics  + b * K);
    const float4* valr = (const float4*)(vals + b * K);

    float4 acc = bias4[colbase];

    float4 wv[2][8];
    float  vv[2][8];

    // Load one batch of 8 (index,val) pairs + issue the 8 weight gathers.
    auto load_batch = [&](int c, int buf) {
        const int4   i0 = icsr[c * 2 + 0];
        const int4   i1 = icsr[c * 2 + 1];
        const float4 f0 = valr[c * 2 + 0];
        const float4 f1 = valr[c * 2 + 1];
        const int   js[8] = {i0.x, i0.y, i0.z, i0.w, i1.x, i1.y, i1.z, i1.w};
        const float fs[8] = {f0.x, f0.y, f0.z, f0.w, f1.x, f1.y, f1.z, f1.w};
        #pragma unroll
        for (int u = 0; u < 8; ++u) {
            vv[buf][u] = (js[u] >= 0) ? fs[u] : 0.0f;        // branchless padding
            const unsigned j = (js[u] >= 0) ? (unsigned)js[u] : 0u;
            wv[buf][u] = w4[(size_t)j * 64 + colbase];       // batched gathers
        }
    };

    load_batch(0, 0);
    #pragma unroll
    for (int c = 0; c < 4; ++c) {
        if (c < 3) load_batch(c + 1, (c + 1) & 1);
        __builtin_amdgcn_sched_barrier(0);   // loads stay above; FMAs below
        const int buf = c & 1;
        #pragma unroll
        for (int u = 0; u < 8; ++u) {
            const float4 w = wv[buf][u];
            const float  v = vv[buf][u];
            acc.x = fmaf(v, w.x, acc.x);
            acc.y = fmaf(v, w.y, acc.y);
            acc.z = fmaf(v, w.z, acc.z);
            acc.w = fmaf(v, w.w, acc.w);
        }
        __builtin_amdgcn_sched_barrier(0);   // keep next batch's loads below prev FMAs
    }

    out4[(size_t)b * 64 + colbase] = acc;
}

extern "C" void kernel_launch(void* const* d_in, const int* in_sizes, int n_in,
                              void* d_out, int out_size, void* d_ws, size_t ws_size,
                              hipStream_t stream) {
    const int*    ics   = (const int*)d_in[0];
    const float*  vals  = (const float*)d_in[1];
    const float4* w4    = (const float4*)d_in[2];
    const float4* bias4 = (const float4*)d_in[3];
    float4*       out4  = (float4*)d_out;

    const int B = in_sizes[0] / K;            // 16384
    const int blocks = ((B + 31) / 32) * 8;   // 32 rows/block x 8 slices = 4096

    hipLaunchKernelGGL(FeatureTransformer_45896020525219_kernel,
                       dim3(blocks), dim3(256), 0, stream,
                       ics, vals, w4, bias4, out4, B);
}

// Round 5
// 135.485 us; speedup vs baseline: 1.3144x; 1.3144x over previous
//
#include <hip/hip_runtime.h>

// Embedding-bag: out[b,:] = bias + sum_k vals[b,k] * weight[ics[b,k],:]
// B=16384, K=32, N_OUT=256.
//
// - 8 column-slices of 32 cols; slice = blockIdx % 8 -> XCD round-robin;
//   per-XCD gather slab = 5.25 MiB -> 81% L2 hit (measured R2: FETCH 97 MB
//   vs 512 MB demand).
// - 4 independent row-chains per lane (rows b, b+32, b+64, b+96), each with
//   its own accumulator: forces >=4 gathers in flight per wave WITHOUT
//   sched fences or register arrays (R4: fences+arrays -> scratch spills,
//   WRITE_SIZE 16->131 MB; R2/R3: single-chain -> compiler sank loads,
//   VGPR=36, ~1-2 in flight, 60 cyc/gather latency-bound).
// - Idx/val loaded as int4/float4 per quad per chain; the 8 lanes of a
//   row-group hit the same address -> single L1 broadcast request.

constexpr int K = 32;

static __device__ __forceinline__ int   seli(const int4& a, int s) {
    return s == 0 ? a.x : s == 1 ? a.y : s == 2 ? a.z : a.w;
}
static __device__ __forceinline__ float self4(const float4& a, int s) {
    return s == 0 ? a.x : s == 1 ? a.y : s == 2 ? a.z : a.w;
}

__global__ __launch_bounds__(256) void FeatureTransformer_45896020525219_kernel(
    const int* __restrict__ ics,
    const float* __restrict__ vals,
    const float4* __restrict__ w4,     // [N_IN * 64]
    const float4* __restrict__ bias4,  // [64]
    float4* __restrict__ out4,         // [B * 64]
    int B)
{
    const int lane   = threadIdx.x & 63;
    const int wave   = threadIdx.x >> 6;
    const int slice  = blockIdx.x & 7;   // -> XCD (L2 locality)
    const int rowblk = blockIdx.x >> 3;

    const int r  = lane >> 3;            // row-group 0..7 within wave
    const int c4 = lane & 7;             // float4-column within the 32-col slice
    const int b0 = rowblk * 128 + wave * 8 + r;   // chains: b0, b0+32, b0+64, b0+96
    if (b0 + 96 >= B + 96) return;       // (always false for B=16384; keeps codegen)

    const int colbase = slice * 8 + c4;  // float4 index within the 64 per row

    const int4*   ip0 = (const int4*)  (ics  + (size_t)(b0      ) * K);
    const int4*   ip1 = (const int4*)  (ics  + (size_t)(b0 + 32 ) * K);
    const int4*   ip2 = (const int4*)  (ics  + (size_t)(b0 + 64 ) * K);
    const int4*   ip3 = (const int4*)  (ics  + (size_t)(b0 + 96 ) * K);
    const float4* fp0 = (const float4*)(vals + (size_t)(b0      ) * K);
    const float4* fp1 = (const float4*)(vals + (size_t)(b0 + 32 ) * K);
    const float4* fp2 = (const float4*)(vals + (size_t)(b0 + 64 ) * K);
    const float4* fp3 = (const float4*)(vals + (size_t)(b0 + 96 ) * K);

    const float4 bv = bias4[colbase];
    float4 acc0 = bv, acc1 = bv, acc2 = bv, acc3 = bv;

    #pragma unroll
    for (int c = 0; c < 8; ++c) {        // k-quad
        const int4   i0 = ip0[c];  const float4 g0 = fp0[c];
        const int4   i1 = ip1[c];  const float4 g1 = fp1[c];
        const int4   i2 = ip2[c];  const float4 g2 = fp2[c];
        const int4   i3 = ip3[c];  const float4 g3 = fp3[c];

        #pragma unroll
        for (int s = 0; s < 4; ++s) {    // k within quad (compile-time)
            const int j0 = seli(i0, s);  const int j1 = seli(i1, s);
            const int j2 = seli(i2, s);  const int j3 = seli(i3, s);
            const float v0 = (j0 >= 0) ? self4(g0, s) : 0.0f;
            const float v1 = (j1 >= 0) ? self4(g1, s) : 0.0f;
            const float v2 = (j2 >= 0) ? self4(g2, s) : 0.0f;
            const float v3 = (j3 >= 0) ? self4(g3, s) : 0.0f;
            const unsigned u0 = (j0 >= 0) ? (unsigned)j0 : 0u;
            const unsigned u1 = (j1 >= 0) ? (unsigned)j1 : 0u;
            const unsigned u2 = (j2 >= 0) ? (unsigned)j2 : 0u;
            const unsigned u3 = (j3 >= 0) ? (unsigned)j3 : 0u;

            // 4 independent gathers -> 4 in flight even with greedy scheduling
            const float4 w0 = w4[(size_t)u0 * 64 + colbase];
            const float4 w1 = w4[(size_t)u1 * 64 + colbase];
            const float4 w2 = w4[(size_t)u2 * 64 + colbase];
            const float4 w3 = w4[(size_t)u3 * 64 + colbase];

            acc0.x = fmaf(v0, w0.x, acc0.x); acc0.y = fmaf(v0, w0.y, acc0.y);
            acc0.z = fmaf(v0, w0.z, acc0.z); acc0.w = fmaf(v0, w0.w, acc0.w);
            acc1.x = fmaf(v1, w1.x, acc1.x); acc1.y = fmaf(v1, w1.y, acc1.y);
            acc1.z = fmaf(v1, w1.z, acc1.z); acc1.w = fmaf(v1, w1.w, acc1.w);
            acc2.x = fmaf(v2, w2.x, acc2.x); acc2.y = fmaf(v2, w2.y, acc2.y);
            acc2.z = fmaf(v2, w2.z, acc2.z); acc2.w = fmaf(v2, w2.w, acc2.w);
            acc3.x = fmaf(v3, w3.x, acc3.x); acc3.y = fmaf(v3, w3.y, acc3.y);
            acc3.z = fmaf(v3, w3.z, acc3.z); acc3.w = fmaf(v3, w3.w, acc3.w);
        }
    }

    out4[(size_t)(b0      ) * 64 + colbase] = acc0;
    out4[(size_t)(b0 + 32 ) * 64 + colbase] = acc1;
    out4[(size_t)(b0 + 64 ) * 64 + colbase] = acc2;
    out4[(size_t)(b0 + 96 ) * 64 + colbase] = acc3;
}

extern "C" void kernel_launch(void* const* d_in, const int* in_sizes, int n_in,
                              void* d_out, int out_size, void* d_ws, size_t ws_size,
                              hipStream_t stream) {
    const int*    ics   = (const int*)d_in[0];
    const float*  vals  = (const float*)d_in[1];
    const float4* w4    = (const float4*)d_in[2];
    const float4* bias4 = (const float4*)d_in[3];
    float4*       out4  = (float4*)d_out;

    const int B = in_sizes[0] / K;              // 16384
    // 128 rows per block (4 waves x 8 row-groups x 4 chains), 8 slices
    const int blocks = ((B + 127) / 128) * 8;   // 1024

    hipLaunchKernelGGL(FeatureTransformer_45896020525219_kernel,
                       dim3(blocks), dim3(256), 0, stream,
                       ics, vals, w4, bias4, out4, B);
}